// Round 11
// baseline (414.393 us; speedup 1.0000x reference)
//
#include <hip/hip_runtime.h>
#include <hip/hip_bf16.h>
#include <hip/hip_cooperative_groups.h>

namespace cg = cooperative_groups;

// Problem constants (fixed by the reference setup)
constexpr int B  = 8;
constexpr int L  = 1024;
constexpr int S  = 512;
constexpr int VD = 64;    // velocity dim
constexpr int DM = 512;   // d_model == spatial_dim
constexpr int D3 = 192;   // 3 * VD
constexpr int H  = 8;     // heads

typedef __attribute__((ext_vector_type(8))) short s8v;     // 8 bf16 (4 VGPRs)
typedef __attribute__((ext_vector_type(4))) float f4v;     // MFMA accum

__device__ inline unsigned short f2b(float f) {            // f32 -> bf16 RNE
    unsigned int u = __builtin_bit_cast(unsigned int, f);
    u += 0x7fffu + ((u >> 16) & 1u);
    return (unsigned short)(u >> 16);
}
__device__ inline float b2f(unsigned int lo16) {           // bf16 bits -> f32
    return __builtin_bit_cast(float, lo16 << 16);
}

// async global->LDS, 16B per lane (linear LDS dest; source-side swizzle).
__device__ __forceinline__ void gload16(const void* g, void* l) {
    __builtin_amdgcn_global_load_lds(
        (const __attribute__((address_space(1))) void*)g,
        (__attribute__((address_space(3))) void*)l, 16, 0, 0);
}

struct CastArgs {
    const float* src[7];
    unsigned short* dst[7];
    int n[7];
    float scale[7];
};

struct Params {
    const float *xs, *xv, *wg, *w3, *b3, *w5, *b5, *w7, *b7;
    const float *rel, *dww, *dwb, *wq, *wk, *wv, *fcw, *fcbias, *lng, *lnb;
    float* out;
    unsigned short *xs_bf, *xv_bf, *wq_bf, *wk_bf, *wv_bf, *fcw_bf, *wg_bf;
    unsigned short *WpeT, *Cp, *WkEff, *Ckb;        // WkEff/Ckb are 2x arrays
    unsigned short *gamma_bf, *qbuf, *kvbuf, *attn_bf, *fcb;
};

// ===========================================================================
// Shared device bodies (identical math to the round-9 proven kernels)
// ===========================================================================

// 128x128 NT MFMA GEMM body (bf16 out, optional f32 bias).
__device__ __forceinline__ void gemm128_body(
    const unsigned short* __restrict__ A, const unsigned short* __restrict__ Bm,
    unsigned short* __restrict__ C, const float* __restrict__ bias,
    int K, int lda, int ldb, int ldc, int m0, int n0,
    unsigned short* As, unsigned short* Bs, int t)
{
    int l = t & 63, w = t >> 6;
    int lx = l & 15, lh = l >> 4;
    int wr = w >> 1, wc = w & 1;

    f4v acc[4][4] = {};

    for (int k0 = 0; k0 < K; k0 += 64) {
        __syncthreads();
#pragma unroll
        for (int p = 0; p < 4; p++) {
            int flat = p * 256 + t;
            int r = flat >> 3, c = flat & 7;
            int csw = (c ^ (r & 7)) * 8;
            gload16(A  + (long)(m0 + r) * lda + k0 + csw, As + flat * 8);
            gload16(Bm + (long)(n0 + r) * ldb + k0 + csw, Bs + flat * 8);
        }
        __syncthreads();
#pragma unroll
        for (int ks = 0; ks < 2; ks++) {
            s8v af[4], bf[4];
#pragma unroll
            for (int i = 0; i < 4; i++) {
                int ra = wr * 64 + i * 16 + lx;
                af[i] = *(const s8v*)(As + ra * 64 + (((ks * 4 + lh) ^ (ra & 7)) * 8));
                int rb = wc * 64 + i * 16 + lx;
                bf[i] = *(const s8v*)(Bs + rb * 64 + (((ks * 4 + lh) ^ (rb & 7)) * 8));
            }
#pragma unroll
            for (int i = 0; i < 4; i++)
#pragma unroll
                for (int j = 0; j < 4; j++)
                    acc[i][j] = __builtin_amdgcn_mfma_f32_16x16x32_bf16(
                        af[i], bf[j], acc[i][j], 0, 0, 0);
        }
    }

#pragma unroll
    for (int i = 0; i < 4; i++) {
#pragma unroll
        for (int r = 0; r < 4; r++) {
            int m = m0 + wr * 64 + i * 16 + lh * 4 + r;
#pragma unroll
            for (int j = 0; j < 4; j++) {
                int n = n0 + wc * 64 + j * 16 + lx;
                float v = acc[i][j][r];
                if (bias) v += bias[n];
                C[(long)m * ldc + n] = f2b(v);
            }
        }
    }
}

// K/V conv-GEMM body (9 x K64 taps; halo via zsrc redirect; bf16 bias).
__device__ __forceinline__ void conv_body(
    const unsigned short* __restrict__ xvb, const unsigned short* __restrict__ Weff,
    const unsigned short* __restrict__ bias2d, unsigned short* __restrict__ Cout,
    const unsigned short* __restrict__ zsrc, int m0, int n0,
    unsigned short* As, unsigned short* Bs, int t)
{
    int l = t & 63, w = t >> 6;
    int lx = l & 15, lh = l >> 4;
    int wr = w >> 1, wc = w & 1;
    int b = m0 >> 9, s0 = m0 & 511;

    f4v acc[4][4] = {};

    for (int j = 0; j < 9; j++) {
        __syncthreads();
#pragma unroll
        for (int p = 0; p < 4; p++) {
            int flat = p * 256 + t;
            int r = flat >> 3, c = flat & 7;
            int csw = (c ^ (r & 7)) * 8;
            int ss = s0 + r + j - 4;
            const unsigned short* asrc = (ss >= 0 && ss < S)
                ? xvb + ((long)b * S + ss) * VD + csw : zsrc;
            gload16(asrc, As + flat * 8);
            gload16(Weff + (long)(n0 + r) * 640 + j * 64 + csw, Bs + flat * 8);
        }
        __syncthreads();
#pragma unroll
        for (int ks = 0; ks < 2; ks++) {
            s8v af[4], bf[4];
#pragma unroll
            for (int i = 0; i < 4; i++) {
                int ra = wr * 64 + i * 16 + lx;
                af[i] = *(const s8v*)(As + ra * 64 + (((ks * 4 + lh) ^ (ra & 7)) * 8));
                int rb = wc * 64 + i * 16 + lx;
                bf[i] = *(const s8v*)(Bs + rb * 64 + (((ks * 4 + lh) ^ (rb & 7)) * 8));
            }
#pragma unroll
            for (int i = 0; i < 4; i++)
#pragma unroll
                for (int jj = 0; jj < 4; jj++)
                    acc[i][jj] = __builtin_amdgcn_mfma_f32_16x16x32_bf16(
                        af[i], bf[jj], acc[i][jj], 0, 0, 0);
        }
    }

#pragma unroll
    for (int i = 0; i < 4; i++) {
#pragma unroll
        for (int r = 0; r < 4; r++) {
            int m = m0 + wr * 64 + i * 16 + lh * 4 + r;
            int s = m & 511;
#pragma unroll
            for (int jj = 0; jj < 4; jj++) {
                int n = n0 + wc * 64 + jj * 16 + lx;
                Cout[(long)m * DM + n] =
                    f2b(acc[i][jj][r] + b2f(bias2d[(long)s * DM + n]));
            }
        }
    }
}

// fc GEMM body: 128(M) x 64(N) tile, 4 waves stacked on M, +f32 bias.
__device__ __forceinline__ void fc64_body(
    const unsigned short* __restrict__ A, const unsigned short* __restrict__ Bm,
    unsigned short* __restrict__ C, const float* __restrict__ bias,
    int m0, int n0, unsigned short* As, unsigned short* Bs, int t)
{
    int l = t & 63, w = t >> 6;
    int lx = l & 15, lh = l >> 4;

    f4v acc[2][4] = {};

    for (int k0 = 0; k0 < DM; k0 += 64) {
        __syncthreads();
#pragma unroll
        for (int p = 0; p < 4; p++) {
            int flat = p * 256 + t;
            int r = flat >> 3, c = flat & 7;
            int csw = (c ^ (r & 7)) * 8;
            gload16(A + (long)(m0 + r) * DM + k0 + csw, As + flat * 8);
        }
#pragma unroll
        for (int p = 0; p < 2; p++) {
            int flat = p * 256 + t;
            int r = flat >> 3, c = flat & 7;
            int csw = (c ^ (r & 7)) * 8;
            gload16(Bm + (long)(n0 + r) * DM + k0 + csw, Bs + flat * 8);
        }
        __syncthreads();
#pragma unroll
        for (int ks = 0; ks < 2; ks++) {
            s8v af[2], bf[4];
#pragma unroll
            for (int i = 0; i < 2; i++) {
                int ra = w * 32 + i * 16 + lx;
                af[i] = *(const s8v*)(As + ra * 64 + (((ks * 4 + lh) ^ (ra & 7)) * 8));
            }
#pragma unroll
            for (int j = 0; j < 4; j++) {
                int rb = j * 16 + lx;
                bf[j] = *(const s8v*)(Bs + rb * 64 + (((ks * 4 + lh) ^ (rb & 7)) * 8));
            }
#pragma unroll
            for (int i = 0; i < 2; i++)
#pragma unroll
                for (int j = 0; j < 4; j++)
                    acc[i][j] = __builtin_amdgcn_mfma_f32_16x16x32_bf16(
                        af[i], bf[j], acc[i][j], 0, 0, 0);
        }
    }

#pragma unroll
    for (int i = 0; i < 2; i++) {
#pragma unroll
        for (int r = 0; r < 4; r++) {
            int m = m0 + w * 32 + i * 16 + lh * 4 + r;
#pragma unroll
            for (int j = 0; j < 4; j++) {
                int n = n0 + j * 16 + lx;
                C[(long)m * DM + n] = f2b(acc[i][j][r] + bias[n]);
            }
        }
    }
}

// One 64x512 attention tile (no-max base-2 softmax; T14 prefetch; T5 setprio).
__device__ __forceinline__ void attn_tile(
    const unsigned short* __restrict__ qg, const unsigned short* __restrict__ kg,
    const unsigned short* __restrict__ vg, unsigned short* __restrict__ obase,
    unsigned short* Qs, unsigned short* Ks, unsigned short* Vt, unsigned short* Ps,
    int t)
{
    int l = t & 63, w = t >> 6, lx = l & 15, lh = l >> 4;
    int kr0 = t >> 3, kc = t & 7;
    int vs = t & 63, vdq = t >> 6;

#pragma unroll
    for (int pp = 0; pp < 2; pp++) {
        int flat = pp * 256 + t;
        int r = flat >> 3, c = flat & 7;
        s8v v = *(const s8v*)(qg + (long)r * DM + c * 8);
        *(s8v*)(Qs + r * 64 + ((c ^ (r & 7)) * 8)) = v;
    }

    s8v k0, k1, v0, v1;
    auto loadKV = [&](int st) {
        k0 = *(const s8v*)(kg + (long)(st * 64 + kr0) * DM + kc * 8);
        k1 = *(const s8v*)(kg + (long)(st * 64 + 32 + kr0) * DM + kc * 8);
        const unsigned short* vp = vg + (long)(st * 64 + vs) * DM + vdq * 16;
        v0 = *(const s8v*)(vp);
        v1 = *(const s8v*)(vp + 8);
    };
    auto writeKV = [&]() {
        *(s8v*)(Ks + kr0 * 64 + ((kc ^ (kr0 & 7)) * 8)) = k0;
        int r2 = 32 + kr0;
        *(s8v*)(Ks + r2 * 64 + ((kc ^ (r2 & 7)) * 8)) = k1;
#pragma unroll
        for (int e = 0; e < 8; e++) {
            int d1 = vdq * 16 + e;
            Vt[d1 * 64 + (((vs >> 3) ^ (d1 & 7)) * 8) + (vs & 7)] = (unsigned short)v0[e];
            int d2 = vdq * 16 + 8 + e;
            Vt[d2 * 64 + (((vs >> 3) ^ (d2 & 7)) * 8) + (vs & 7)] = (unsigned short)v1[e];
        }
    };

    loadKV(0);
    writeKV();
    __syncthreads();

    float lrow[4] = {0.f, 0.f, 0.f, 0.f};
    f4v oacc[4] = {};

    for (int st = 0; st < S / 64; st++) {
        if (st < S / 64 - 1) loadKV(st + 1);

        f4v pacc[4] = {};
        __builtin_amdgcn_s_setprio(1);
#pragma unroll
        for (int ks = 0; ks < 2; ks++) {
            int qr = w * 16 + lx;
            s8v a = *(const s8v*)(Qs + qr * 64 + (((ks * 4 + lh) ^ (qr & 7)) * 8));
#pragma unroll
            for (int jf = 0; jf < 4; jf++) {
                int kr = jf * 16 + lx;
                s8v bf = *(const s8v*)(Ks + kr * 64 + (((ks * 4 + lh) ^ (kr & 7)) * 8));
                pacc[jf] = __builtin_amdgcn_mfma_f32_16x16x32_bf16(a, bf, pacc[jf], 0, 0, 0);
            }
        }
        __builtin_amdgcn_s_setprio(0);

#pragma unroll
        for (int r = 0; r < 4; r++) {
            int prow = w * 16 + lh * 4 + r;
#pragma unroll
            for (int jf = 0; jf < 4; jf++) {
                float pe = __builtin_amdgcn_exp2f(pacc[jf][r]);
                lrow[r] += pe;
                int col = jf * 16 + lx;
                Ps[prow * 64 + (((col >> 3) ^ (prow & 7)) * 8) + (col & 7)] = f2b(pe);
            }
        }
        asm volatile("s_waitcnt lgkmcnt(0)" ::: "memory");

        __builtin_amdgcn_s_setprio(1);
#pragma unroll
        for (int ks2 = 0; ks2 < 2; ks2++) {
            int pr = w * 16 + lx;
            s8v pa = *(const s8v*)(Ps + pr * 64 + (((ks2 * 4 + lh) ^ (pr & 7)) * 8));
#pragma unroll
            for (int df = 0; df < 4; df++) {
                int vr = df * 16 + lx;
                s8v vf = *(const s8v*)(Vt + vr * 64 + (((ks2 * 4 + lh) ^ (vr & 7)) * 8));
                oacc[df] = __builtin_amdgcn_mfma_f32_16x16x32_bf16(pa, vf, oacc[df], 0, 0, 0);
            }
        }
        __builtin_amdgcn_s_setprio(0);
        __syncthreads();
        if (st < S / 64 - 1) {
            writeKV();
            __syncthreads();
        }
    }

#pragma unroll
    for (int r = 0; r < 4; r++) {
        float ls = lrow[r];
#pragma unroll
        for (int msk = 1; msk < 16; msk <<= 1) ls += __shfl_xor(ls, msk);
        float invl = 1.f / ls;
#pragma unroll
        for (int df = 0; df < 4; df++)
            obase[(long)(w * 16 + lh * 4 + r) * DM + df * 16 + lx] = f2b(oacc[df][r] * invl);
    }
}

// ===========================================================================
// FALLBACK PATH — round-9 proven kernels (6 launches)
// ===========================================================================

__global__ __launch_bounds__(256) void prep_cast_k(
    CastArgs a,
    const float* __restrict__ w3, const float* __restrict__ w5,
    const float* __restrict__ w7, const float* __restrict__ dw_w,
    const float* __restrict__ rel_table, const float* __restrict__ b3,
    const float* __restrict__ b5, const float* __restrict__ b7,
    const float* __restrict__ dw_b,
    unsigned short* __restrict__ WpeT, unsigned short* __restrict__ Cp)
{
    int t = threadIdx.x;
    int y = blockIdx.y;

    if (y < 7) {
        const float* s = a.src[y];
        unsigned short* d = a.dst[y];
        int n = a.n[y];
        float sc = a.scale[y];
        for (long i = (long)(blockIdx.x * 256 + t) * 4; i < n;
             i += (long)gridDim.x * 1024) {
            float4 f = *(const float4*)(s + i);
            ushort4 o;
            o.x = f2b(f.x * sc); o.y = f2b(f.y * sc);
            o.z = f2b(f.z * sc); o.w = f2b(f.w * sc);
            *(ushort4*)(d + i) = o;
        }
        return;
    }

    if (t >= 192) return;
    int o = t;
    float inv = 1.0f / S;

    if (blockIdx.x < 640) {
        int n = blockIdx.x;
        if (n >= 576) { WpeT[n * D3 + o] = 0; return; }
        int j = n >> 6, c = n & 63, delta = j - 4;
        const float* w; int KW, P, oo;
        if (o < 64)       { w = w3; KW = 3; P = 1; oo = o; }
        else if (o < 128) { w = w5; KW = 5; P = 2; oo = o - 64; }
        else              { w = w7; KW = 7; P = 3; oo = o - 128; }
        float mu0 = dw_w[o * 3 + 0] * inv;
        float mu1 = 1.f + (dw_w[o * 3 + 1] - 1.f) * inv;
        float mu2 = dw_w[o * 3 + 2] * inv;
        float acc = 0.f;
        int k;
        k = delta + 1 + P; if (k >= 0 && k < KW) acc += mu0 * w[(oo * 64 + c) * KW + k];
        k = delta + P;     if (k >= 0 && k < KW) acc += mu1 * w[(oo * 64 + c) * KW + k];
        k = delta - 1 + P; if (k >= 0 && k < KW) acc += mu2 * w[(oo * 64 + c) * KW + k];
        WpeT[n * D3 + o] = f2b(acc);
        return;
    }

    int j = blockIdx.x - 640;
    float acc = 0.f;
#pragma unroll
    for (int r = 1; r < 60; r++) {
        int i = j - (r - 30);
        if (i >= 0 && i < S) acc += rel_table[r * D3 + o];
    }
    float c60 = (float)max(0, j - 29);
    float c0  = (float)max(0, (S - 30) - j);
    acc += c60 * rel_table[60 * D3 + o] + c0 * rel_table[0 * D3 + o];
    float mean_rel = acc * inv;

    float bo  = (o < 64) ? b3[o] : (o < 128) ? b5[o - 64] : b7[o - 128];
    float dw0 = dw_w[o * 3], dw1 = dw_w[o * 3 + 1], dw2 = dw_w[o * 3 + 2];
    float r29 = rel_table[29 * D3 + o], r30 = rel_table[30 * D3 + o],
          r31 = rel_table[31 * D3 + o];
    float alpha = 1.f + (dw1 - 1.f) * inv, beta = dw0 * inv, gamma = dw2 * inv;

    float cp = mean_rel + bo * alpha + (dw1 * r30 + dw_b[o] - r30) * inv;
    if (j > 0)     cp += beta * bo + dw0 * r29 * inv;
    if (j < S - 1) cp += gamma * bo + dw2 * r31 * inv;
    Cp[j * D3 + o] = f2b(cp);
}

__global__ __launch_bounds__(256) void pre_gemm5_k(
    const unsigned short* __restrict__ wk_bf,
    const unsigned short* __restrict__ wv_bf,
    const unsigned short* __restrict__ WpeT,
    const unsigned short* __restrict__ Cp,
    const unsigned short* __restrict__ xv_bf,
    const unsigned short* __restrict__ wg_bf,
    unsigned short* __restrict__ WEff,
    unsigned short* __restrict__ Cb,
    unsigned short* __restrict__ gamma_bf)
{
    int z = blockIdx.z, mx = blockIdx.x, ny = blockIdx.y;
    const unsigned short *A, *Bm;
    unsigned short* C;
    int K, lda, ldb, ldc;
    if (z < 2) {
        if (mx >= 4) return;
        A = z ? wv_bf : wk_bf; Bm = WpeT; C = WEff + (long)z * DM * 640;
        K = D3; lda = D3; ldb = D3; ldc = 640;
    } else if (z < 4) {
        if (mx >= 4 || ny >= 4) return;
        A = Cp; Bm = (z == 2) ? wk_bf : wv_bf; C = Cb + (long)(z - 2) * S * DM;
        K = D3; lda = D3; ldb = D3; ldc = DM;
    } else {
        if (ny >= 4) return;
        A = xv_bf; Bm = wg_bf; C = gamma_bf;
        K = VD; lda = VD; ldb = VD; ldc = DM;
    }

    __shared__ __align__(16) unsigned short As[128 * 64];
    __shared__ __align__(16) unsigned short Bs[128 * 64];
    gemm128_body(A, Bm, C, nullptr, K, lda, ldb, ldc,
                 mx * 128, ny * 128, As, Bs, threadIdx.x);
}

__global__ __launch_bounds__(256) void qconv_k(
    const unsigned short* __restrict__ xs_bf,
    const unsigned short* __restrict__ wq_bf,
    unsigned short* __restrict__ qbuf,
    const unsigned short* __restrict__ xvb,
    const unsigned short* __restrict__ Weff0,
    const unsigned short* __restrict__ bias0,
    unsigned short* __restrict__ Cout0,
    const unsigned short* __restrict__ zsrc)
{
    __shared__ __align__(16) unsigned short As[128 * 64];
    __shared__ __align__(16) unsigned short Bs[128 * 64];
    int zt = blockIdx.z, t = threadIdx.x;

    if (zt == 0) {
        gemm128_body(xs_bf, wq_bf, qbuf, nullptr, DM, DM, DM, DM,
                     blockIdx.x * 128, blockIdx.y * 128, As, Bs, t);
        return;
    }
    if (blockIdx.x >= 32) return;
    int z = zt - 1;
    conv_body(xvb, Weff0 + (long)z * DM * 640, bias0 + (long)z * S * DM,
              Cout0 + (long)z * B * S * DM, zsrc,
              blockIdx.x * 128, blockIdx.y * 128, As, Bs, t);
}

__global__ __launch_bounds__(256) void attn_mfma_k(
    const unsigned short* __restrict__ qb, const unsigned short* __restrict__ kb,
    const unsigned short* __restrict__ vb, unsigned short* __restrict__ ob)
{
    __shared__ __align__(16) unsigned short Qs[64 * 64];
    __shared__ __align__(16) unsigned short Ks[64 * 64];
    __shared__ __align__(16) unsigned short Vt[64 * 64];
    __shared__ __align__(16) unsigned short Ps[64 * 64];

    int lt = blockIdx.x, h = blockIdx.y, b = blockIdx.z;
    attn_tile(qb + ((long)(b * L + lt * 64)) * DM + h * 64,
              kb + ((long)b * S) * DM + h * 64,
              vb + ((long)b * S) * DM + h * 64,
              ob + ((long)(b * L + lt * 64)) * DM + h * 64,
              Qs, Ks, Vt, Ps, threadIdx.x);
}

__global__ __launch_bounds__(256) void gemm_fc_k(
    const unsigned short* __restrict__ A, const unsigned short* __restrict__ Bm,
    unsigned short* __restrict__ Cout, const float* __restrict__ bias)
{
    __shared__ __align__(16) unsigned short As[128 * 64];
    __shared__ __align__(16) unsigned short Bs[128 * 64];
    gemm128_body(A, Bm, Cout, bias, DM, DM, DM, DM,
                 blockIdx.x * 128, blockIdx.y * 128, As, Bs, threadIdx.x);
}

__global__ __launch_bounds__(256) void final_k(
    const float* __restrict__ xs, const unsigned short* __restrict__ fcb,
    const unsigned short* __restrict__ gb,
    const float* __restrict__ ln_g, const float* __restrict__ ln_b,
    float* __restrict__ out)
{
    int bl = blockIdx.x;
    int b = bl >> 10, lq = bl & 1023;
    int t = threadIdx.x;
    int d0 = t * 2;
    const unsigned short* g = gb + ((long)b * S + (lq & 511)) * DM;

    __shared__ float red[2][4];

    float2 xv2 = *(const float2*)(xs + (long)bl * DM + d0);
    unsigned int fp = *(const unsigned int*)(fcb + (long)bl * DM + d0);
    unsigned int gp = *(const unsigned int*)(g + d0);

    float fo0 = b2f(fp & 0xffffu), fo1 = b2f(fp >> 16);
    float ga0 = 1.f / (1.f + __expf(-b2f(gp & 0xffffu)));
    float ga1 = 1.f / (1.f + __expf(-b2f(gp >> 16)));
    float r0 = xv2.x + ga0 * fo0;
    float r1 = xv2.y + ga1 * fo1;

    float sum = r0 + r1, sumsq = r0 * r0 + r1 * r1;
#pragma unroll
    for (int msk = 1; msk < 64; msk <<= 1) {
        sum   += __shfl_xor(sum, msk);
        sumsq += __shfl_xor(sumsq, msk);
    }
    int wave = t >> 6;
    if ((t & 63) == 0) { red[0][wave] = sum; red[1][wave] = sumsq; }
    __syncthreads();
    float tot   = red[0][0] + red[0][1] + red[0][2] + red[0][3];
    float totsq = red[1][0] + red[1][1] + red[1][2] + red[1][3];

    float mu  = tot * (1.0f / DM);
    float var = totsq * (1.0f / DM) - mu * mu;
    float inv = rsqrtf(var + 1e-5f);

    float2 lg = *(const float2*)(ln_g + d0);
    float2 lb = *(const float2*)(ln_b + d0);
    float2 o;
    o.x = (r0 - mu) * inv * lg.x + lb.x;
    o.y = (r1 - mu) * inv * lg.y + lb.y;
    *(float2*)(out + (long)bl * DM + d0) = o;
}

// ===========================================================================
// COOPERATIVE PATH — single fused kernel, grid-size-agnostic phases.
// ===========================================================================
__global__ __launch_bounds__(256, 2) void fused_k(Params p) {
    __shared__ __align__(16) unsigned short lds[16384];    // 32 KB
    unsigned short* As = lds;
    unsigned short* Bs = lds + 8192;

    int t   = threadIdx.x;
    int blk = blockIdx.x;
    int nbl = gridDim.x;
    cg::grid_group grid = cg::this_grid();

    // ---------------- P0: casts + tables ----------------
    {
        const float* srcs[7] = {p.xs, p.xv, p.wq, p.wk, p.wv, p.fcw, p.wg};
        unsigned short* dsts[7] = {p.xs_bf, p.xv_bf, p.wq_bf, p.wk_bf,
                                   p.wv_bf, p.fcw_bf, p.wg_bf};
        const int   ns[7] = {B * L * DM, B * S * VD, DM * DM, DM * D3,
                             DM * D3, DM * DM, DM * VD};
        const float scs[7] = {1.f, 1.f, 0.125f * 1.44269504089f, 1.f, 1.f, 1.f, 1.f};
#pragma unroll
        for (int id = 0; id < 7; id++) {
            const float* s = srcs[id];
            unsigned short* d = dsts[id];
            float sc = scs[id];
            for (long i = (long)(blk * 256 + t) * 4; i < ns[id];
                 i += (long)nbl * 1024) {
                float4 f = *(const float4*)(s + i);
                ushort4 o;
                o.x = f2b(f.x * sc); o.y = f2b(f.y * sc);
                o.z = f2b(f.z * sc); o.w = f2b(f.w * sc);
                *(ushort4*)(d + i) = o;
            }
        }

        float inv = 1.0f / S;
        if (t < 192) {
            int o = t;
            for (int row = blk; row < 1152; row += nbl) {
                if (row < 640) {
                    int n = row;
                    if (n >= 576) { p.WpeT[n * D3 + o] = 0; continue; }
                    int j = n >> 6, c = n & 63, delta = j - 4;
                    const float* w; int KW, P, oo;
                    if (o < 64)       { w = p.w3; KW = 3; P = 1; oo = o; }
                    else if (o < 128) { w = p.w5; KW = 5; P = 2; oo = o - 64; }
                    else              { w = p.w7; KW = 7; P = 3; oo = o - 128; }
                    float mu0 = p.dww[o * 3 + 0] * inv;
                    float mu1 = 1.f + (p.dww[o * 3 + 1] - 1.f) * inv;
                    float mu2 = p.dww[o * 3 + 2] * inv;
                    float acc = 0.f;
                    int k;
                    k = delta + 1 + P; if (k >= 0 && k < KW) acc += mu0 * w[(oo * 64 + c) * KW + k];
                    k = delta + P;     if (k >= 0 && k < KW) acc += mu1 * w[(oo * 64 + c) * KW + k];
                    k = delta - 1 + P; if (k >= 0 && k < KW) acc += mu2 * w[(oo * 64 + c) * KW + k];
                    p.WpeT[n * D3 + o] = f2b(acc);
                } else {
                    int j = row - 640;
                    float acc = 0.f;
#pragma unroll
                    for (int r = 1; r < 60; r++) {
                        int i = j - (r - 30);
                        if (i >= 0 && i < S) acc += p.rel[r * D3 + o];
                    }
                    float c60 = (float)max(0, j - 29);
                    float c0  = (float)max(0, (S - 30) - j);
                    acc += c60 * p.rel[60 * D3 + o] + c0 * p.rel[0 * D3 + o];
                    float mean_rel = acc * inv;

                    float bo  = (o < 64) ? p.b3[o] : (o < 128) ? p.b5[o - 64] : p.b7[o - 128];
                    float dw0 = p.dww[o * 3], dw1 = p.dww[o * 3 + 1], dw2 = p.dww[o * 3 + 2];
                    float r29 = p.rel[29 * D3 + o], r30 = p.rel[30 * D3 + o],
                          r31 = p.rel[31 * D3 + o];
                    float alpha = 1.f + (dw1 - 1.f) * inv, beta = dw0 * inv, gamma = dw2 * inv;

                    float cp = mean_rel + bo * alpha + (dw1 * r30 + p.dwb[o] - r30) * inv;
                    if (j > 0)     cp += beta * bo + dw0 * r29 * inv;
                    if (j < S - 1) cp += gamma * bo + dw2 * r31 * inv;
                    p.Cp[j * D3 + o] = f2b(cp);
                }
            }
        }
    }
    grid.sync();

    // ---------------- P1: five small GEMMs (200 virtual blocks) ----------------
    for (int vb = blk; vb < 200; vb += nbl) {
        if (vb < 20) {
            gemm128_body(p.wk_bf, p.WpeT, p.WkEff, nullptr,
                         D3, D3, D3, 640, (vb / 5) * 128, (vb % 5) * 128, As, Bs, t);
        } else if (vb < 40) {
            int i = vb - 20;
            gemm128_body(p.wv_bf, p.WpeT, p.WkEff + (long)DM * 640, nullptr,
                         D3, D3, D3, 640, (i / 5) * 128, (i % 5) * 128, As, Bs, t);
        } else if (vb < 56) {
            int i = vb - 40;
            gemm128_body(p.Cp, p.wk_bf, p.Ckb, nullptr,
                         D3, D3, D3, DM, (i / 4) * 128, (i % 4) * 128, As, Bs, t);
        } else if (vb < 72) {
            int i = vb - 56;
            gemm128_body(p.Cp, p.wv_bf, p.Ckb + (long)S * DM, nullptr,
                         D3, D3, D3, DM, (i / 4) * 128, (i % 4) * 128, As, Bs, t);
        } else {
            int i = vb - 72;
            gemm128_body(p.xv_bf, p.wg_bf, p.gamma_bf, nullptr,
                         VD, VD, VD, DM, (i >> 2) * 128, (i & 3) * 128, As, Bs, t);
        }
        __syncthreads();
    }
    grid.sync();

    // ---------------- P2: Q projection + K/V conv (512 virtual blocks) ----------------
    {
        const unsigned short* zsrc = p.WkEff + 576;
        for (int vb = blk; vb < 512; vb += nbl) {
            if (vb < 256) {
                gemm128_body(p.xs_bf, p.wq_bf, p.qbuf, nullptr,
                             DM, DM, DM, DM, (vb >> 2) * 128, (vb & 3) * 128, As, Bs, t);
            } else {
                int i = vb - 256;
                int z = i >> 7, rem = i & 127;
                conv_body(p.xv_bf, p.WkEff + (long)z * DM * 640,
                          p.Ckb + (long)z * S * DM, p.kvbuf + (long)z * B * S * DM,
                          zsrc, (rem >> 2) * 128, (rem & 3) * 128, As, Bs, t);
            }
            __syncthreads();
        }
    }
    grid.sync();

    // ---------------- P3: attention (1024 virtual tiles) ----------------
    {
        unsigned short* Qs = lds;
        unsigned short* Ks = lds + 4096;
        unsigned short* Vt = lds + 8192;
        unsigned short* Ps = lds + 12288;

        for (int ti = blk; ti < 1024; ti += nbl) {
            int lt = ti & 15, h = (ti >> 4) & 7, b = ti >> 7;
            attn_tile(p.qbuf + ((long)(b * L + lt * 64)) * DM + h * 64,
                      p.kvbuf + ((long)b * S) * DM + h * 64,
                      p.kvbuf + (long)B * S * DM + ((long)b * S) * DM + h * 64,
                      p.attn_bf + ((long)(b * L + lt * 64)) * DM + h * 64,
                      Qs, Ks, Vt, Ps, t);
            __syncthreads();
        }
    }
    grid.sync();

    // ---------------- P4: fc GEMM (512 virtual 128x64 tiles) ----------------
    for (int vb = blk; vb < 512; vb += nbl) {
        fc64_body(p.attn_bf, p.fcw_bf, p.fcb, p.fcbias,
                  (vb >> 3) * 128, (vb & 7) * 64, As, Bs, t);
        __syncthreads();
    }
    grid.sync();

    // ---------------- P5: gated residual + LayerNorm ----------------
    {
        float* red = (float*)lds;
        int d0 = t * 2;
        for (int bl = blk; bl < B * L; bl += nbl) {
            int b = bl >> 10, lq = bl & 1023;
            const unsigned short* g = p.gamma_bf + ((long)b * S + (lq & 511)) * DM;

            float2 xv2 = *(const float2*)(p.xs + (long)bl * DM + d0);
            unsigned int fp = *(const unsigned int*)(p.fcb + (long)bl * DM + d0);
            unsigned int gp = *(const unsigned int*)(g + d0);

            float fo0 = b2f(fp & 0xffffu), fo1 = b2f(fp >> 16);
            float ga0 = 1.f / (1.f + __expf(-b2f(gp & 0xffffu)));
            float ga1 = 1.f / (1.f + __expf(-b2f(gp >> 16)));
            float r0 = xv2.x + ga0 * fo0;
            float r1 = xv2.y + ga1 * fo1;

            float sum = r0 + r1, sumsq = r0 * r0 + r1 * r1;
#pragma unroll
            for (int msk = 1; msk < 64; msk <<= 1) {
                sum   += __shfl_xor(sum, msk);
                sumsq += __shfl_xor(sumsq, msk);
            }
            int wave = t >> 6;
            if ((t & 63) == 0) { red[wave] = sum; red[4 + wave] = sumsq; }
            __syncthreads();
            float tot   = red[0] + red[1] + red[2] + red[3];
            float totsq = red[4] + red[5] + red[6] + red[7];
            __syncthreads();

            float mu  = tot * (1.0f / DM);
            float var = totsq * (1.0f / DM) - mu * mu;
            float inv = rsqrtf(var + 1e-5f);

            float2 lg = *(const float2*)(p.lng + d0);
            float2 lb = *(const float2*)(p.lnb + d0);
            float2 o;
            o.x = (r0 - mu) * inv * lg.x + lb.x;
            o.y = (r1 - mu) * inv * lg.y + lb.y;
            *(float2*)(p.out + (long)bl * DM + d0) = o;
        }
    }
}

// ---------------------------------------------------------------------------
// Launch: query-gated cooperative attempt with proven 6-launch fallback.
// ---------------------------------------------------------------------------
extern "C" void kernel_launch(void* const* d_in, const int* in_sizes, int n_in,
                              void* d_out, int out_size, void* d_ws, size_t ws_size,
                              hipStream_t stream) {
    (void)in_sizes; (void)n_in; (void)out_size; (void)ws_size;

    char* pw = (char*)d_ws;
    auto alloc = [&](size_t bytes) {
        char* r = pw;
        pw += (bytes + 255) & ~(size_t)255;
        return r;
    };

    Params p;
    p.xs  = (const float*)d_in[0];
    p.xv  = (const float*)d_in[1];
    p.wg  = (const float*)d_in[2];
    p.w3  = (const float*)d_in[3];
    p.b3  = (const float*)d_in[4];
    p.w5  = (const float*)d_in[5];
    p.b5  = (const float*)d_in[6];
    p.w7  = (const float*)d_in[7];
    p.b7  = (const float*)d_in[8];
    p.rel = (const float*)d_in[9];
    p.dww = (const float*)d_in[10];
    p.dwb = (const float*)d_in[11];
    p.wq  = (const float*)d_in[12];
    p.wk  = (const float*)d_in[13];
    p.wv  = (const float*)d_in[14];
    p.fcw = (const float*)d_in[15];
    p.fcbias = (const float*)d_in[16];
    p.lng = (const float*)d_in[17];
    p.lnb = (const float*)d_in[18];
    p.out = (float*)d_out;

    p.gamma_bf = (unsigned short*)alloc((size_t)B * S * DM * 2);
    p.fcb      = (unsigned short*)alloc((size_t)B * L * DM * 2);
    p.xs_bf    = (unsigned short*)alloc((size_t)B * L * DM * 2);
    p.xv_bf    = (unsigned short*)alloc((size_t)B * S * VD * 2);
    p.qbuf     = (unsigned short*)alloc((size_t)B * L * DM * 2);
    p.kvbuf    = (unsigned short*)alloc((size_t)2 * B * S * DM * 2);   // K then V
    p.attn_bf  = (unsigned short*)alloc((size_t)B * L * DM * 2);
    p.wq_bf    = (unsigned short*)alloc((size_t)DM * DM * 2);
    p.wk_bf    = (unsigned short*)alloc((size_t)DM * D3 * 2);
    p.wv_bf    = (unsigned short*)alloc((size_t)DM * D3 * 2);
    p.fcw_bf   = (unsigned short*)alloc((size_t)DM * DM * 2);
    p.wg_bf    = (unsigned short*)alloc((size_t)DM * VD * 2);
    p.WpeT     = (unsigned short*)alloc((size_t)640 * D3 * 2);
    p.Cp       = (unsigned short*)alloc((size_t)S * D3 * 2);
    p.WkEff    = (unsigned short*)alloc((size_t)2 * DM * 640 * 2);     // K then V
    p.Ckb      = (unsigned short*)alloc((size_t)2 * S * DM * 2);       // K then V

    // ---- cooperative attempt (query-gated, error-checked) ----
    int dev = 0, coop = 0, ncu = 0, maxb = 0;
    bool ok = (hipGetDevice(&dev) == hipSuccess);
    if (ok) ok = (hipDeviceGetAttribute(&coop, hipDeviceAttributeCooperativeLaunch, dev)
                  == hipSuccess) && coop;
    if (ok) ok = (hipDeviceGetAttribute(&ncu, hipDeviceAttributeMultiprocessorCount, dev)
                  == hipSuccess) && ncu > 0;
    if (ok) ok = (hipOccupancyMaxActiveBlocksPerMultiprocessor(&maxb, fused_k, 256, 0)
                  == hipSuccess) && maxb >= 1;
    if (ok) {
        int g = maxb * ncu;
        if (g > 512) g = 512;
        void* args[] = {&p};
        if (hipLaunchCooperativeKernel((const void*)fused_k, dim3(g), dim3(256),
                                       args, 0, stream) == hipSuccess)
            return;
        (void)hipGetLastError();     // clear sticky error, fall through
    }

    // ---- fallback: round-9 proven 6-launch path ----
    CastArgs ca;
    ca.src[0] = p.xs;  ca.dst[0] = p.xs_bf;  ca.n[0] = B * L * DM; ca.scale[0] = 1.f;
    ca.src[1] = p.xv;  ca.dst[1] = p.xv_bf;  ca.n[1] = B * S * VD; ca.scale[1] = 1.f;
    ca.src[2] = p.wq;  ca.dst[2] = p.wq_bf;  ca.n[2] = DM * DM;    ca.scale[2] = 0.125f * 1.44269504089f;
    ca.src[3] = p.wk;  ca.dst[3] = p.wk_bf;  ca.n[3] = DM * D3;    ca.scale[3] = 1.f;
    ca.src[4] = p.wv;  ca.dst[4] = p.wv_bf;  ca.n[4] = DM * D3;    ca.scale[4] = 1.f;
    ca.src[5] = p.fcw; ca.dst[5] = p.fcw_bf; ca.n[5] = DM * DM;    ca.scale[5] = 1.f;
    ca.src[6] = p.wg;  ca.dst[6] = p.wg_bf;  ca.n[6] = DM * VD;    ca.scale[6] = 1.f;

    prep_cast_k<<<dim3(1152, 8), 256, 0, stream>>>(
        ca, p.w3, p.w5, p.w7, p.dww, p.rel, p.b3, p.b5, p.b7, p.dwb, p.WpeT, p.Cp);

    pre_gemm5_k<<<dim3(32, 5, 5), 256, 0, stream>>>(
        p.wk_bf, p.wv_bf, p.WpeT, p.Cp, p.xv_bf, p.wg_bf, p.WkEff, p.Ckb, p.gamma_bf);

    qconv_k<<<dim3(64, 4, 3), 256, 0, stream>>>(
        p.xs_bf, p.wq_bf, p.qbuf, p.xv_bf, p.WkEff, p.Ckb, p.kvbuf, p.WkEff + 576);

    attn_mfma_k<<<dim3(L / 64, H, B), 256, 0, stream>>>(
        p.qbuf, p.kvbuf, p.kvbuf + (long)B * S * DM, p.attn_bf);

    gemm_fc_k<<<dim3(64, 4), 256, 0, stream>>>(p.attn_bf, p.fcw_bf, p.fcb, p.fcbias);

    final_k<<<dim3(B * L), 256, 0, stream>>>(
        p.xs, p.fcb, p.gamma_bf, p.lng, p.lnb, p.out);
}

// Round 12
// 192.115 us; speedup vs baseline: 2.1570x; 2.1570x over previous
//
#include <hip/hip_runtime.h>
#include <hip/hip_bf16.h>

// Problem constants (fixed by the reference setup)
constexpr int B  = 8;
constexpr int L  = 1024;
constexpr int S  = 512;
constexpr int VD = 64;    // velocity dim
constexpr int DM = 512;   // d_model == spatial_dim
constexpr int D3 = 192;   // 3 * VD
constexpr int H  = 8;     // heads

typedef __attribute__((ext_vector_type(8))) short s8v;     // 8 bf16 (4 VGPRs)
typedef __attribute__((ext_vector_type(4))) float f4v;     // MFMA accum

__device__ inline unsigned short f2b(float f) {            // f32 -> bf16 RNE
    unsigned int u = __builtin_bit_cast(unsigned int, f);
    u += 0x7fffu + ((u >> 16) & 1u);
    return (unsigned short)(u >> 16);
}
__device__ inline float b2f(unsigned int lo16) {           // bf16 bits -> f32
    return __builtin_bit_cast(float, lo16 << 16);
}

// async global->LDS, 16B per lane (linear LDS dest; source-side swizzle).
__device__ __forceinline__ void gload16(const void* g, void* l) {
    __builtin_amdgcn_global_load_lds(
        (const __attribute__((address_space(1))) void*)g,
        (__attribute__((address_space(3))) void*)l, 16, 0, 0);
}

struct CastArgs {
    const float* src[7];
    unsigned short* dst[7];
    int n[7];
    float scale[7];
};

// ---------------------------------------------------------------------------
// 128x128 NT MFMA GEMM body (bf16 out, optional f32 bias).
// ---------------------------------------------------------------------------
__device__ __forceinline__ void gemm128_body(
    const unsigned short* __restrict__ A, const unsigned short* __restrict__ Bm,
    unsigned short* __restrict__ C, const float* __restrict__ bias,
    int K, int lda, int ldb, int ldc, int m0, int n0,
    unsigned short* As, unsigned short* Bs, int t)
{
    int l = t & 63, w = t >> 6;
    int lx = l & 15, lh = l >> 4;
    int wr = w >> 1, wc = w & 1;

    f4v acc[4][4] = {};

    for (int k0 = 0; k0 < K; k0 += 64) {
        __syncthreads();
#pragma unroll
        for (int p = 0; p < 4; p++) {
            int flat = p * 256 + t;
            int r = flat >> 3, c = flat & 7;
            int csw = (c ^ (r & 7)) * 8;
            gload16(A  + (long)(m0 + r) * lda + k0 + csw, As + flat * 8);
            gload16(Bm + (long)(n0 + r) * ldb + k0 + csw, Bs + flat * 8);
        }
        __syncthreads();
#pragma unroll
        for (int ks = 0; ks < 2; ks++) {
            s8v af[4], bf[4];
#pragma unroll
            for (int i = 0; i < 4; i++) {
                int ra = wr * 64 + i * 16 + lx;
                af[i] = *(const s8v*)(As + ra * 64 + (((ks * 4 + lh) ^ (ra & 7)) * 8));
                int rb = wc * 64 + i * 16 + lx;
                bf[i] = *(const s8v*)(Bs + rb * 64 + (((ks * 4 + lh) ^ (rb & 7)) * 8));
            }
#pragma unroll
            for (int i = 0; i < 4; i++)
#pragma unroll
                for (int j = 0; j < 4; j++)
                    acc[i][j] = __builtin_amdgcn_mfma_f32_16x16x32_bf16(
                        af[i], bf[j], acc[i][j], 0, 0, 0);
        }
    }

#pragma unroll
    for (int i = 0; i < 4; i++) {
#pragma unroll
        for (int r = 0; r < 4; r++) {
            int m = m0 + wr * 64 + i * 16 + lh * 4 + r;
#pragma unroll
            for (int j = 0; j < 4; j++) {
                int n = n0 + wc * 64 + j * 16 + lx;
                float v = acc[i][j][r];
                if (bias) v += bias[n];
                C[(long)m * ldc + n] = f2b(v);
            }
        }
    }
}

// ---------------------------------------------------------------------------
// 128(M) x 64(N) GEMM body, 4 waves stacked on M, optional f32 bias.
// (verified in round-11's passing cooperative run)
// ---------------------------------------------------------------------------
__device__ __forceinline__ void gemm_mn64_body(
    const unsigned short* __restrict__ A, const unsigned short* __restrict__ Bm,
    unsigned short* __restrict__ C, const float* __restrict__ bias,
    int K, int m0, int n0, unsigned short* As, unsigned short* Bs, int t)
{
    int l = t & 63, w = t >> 6;
    int lx = l & 15, lh = l >> 4;

    f4v acc[2][4] = {};

    for (int k0 = 0; k0 < K; k0 += 64) {
        __syncthreads();
#pragma unroll
        for (int p = 0; p < 4; p++) {
            int flat = p * 256 + t;
            int r = flat >> 3, c = flat & 7;
            int csw = (c ^ (r & 7)) * 8;
            gload16(A + (long)(m0 + r) * DM + k0 + csw, As + flat * 8);
        }
#pragma unroll
        for (int p = 0; p < 2; p++) {
            int flat = p * 256 + t;
            int r = flat >> 3, c = flat & 7;
            int csw = (c ^ (r & 7)) * 8;
            gload16(Bm + (long)(n0 + r) * DM + k0 + csw, Bs + flat * 8);
        }
        __syncthreads();
#pragma unroll
        for (int ks = 0; ks < 2; ks++) {
            s8v af[2], bf[4];
#pragma unroll
            for (int i = 0; i < 2; i++) {
                int ra = w * 32 + i * 16 + lx;
                af[i] = *(const s8v*)(As + ra * 64 + (((ks * 4 + lh) ^ (ra & 7)) * 8));
            }
#pragma unroll
            for (int j = 0; j < 4; j++) {
                int rb = j * 16 + lx;
                bf[j] = *(const s8v*)(Bs + rb * 64 + (((ks * 4 + lh) ^ (rb & 7)) * 8));
            }
#pragma unroll
            for (int i = 0; i < 2; i++)
#pragma unroll
                for (int j = 0; j < 4; j++)
                    acc[i][j] = __builtin_amdgcn_mfma_f32_16x16x32_bf16(
                        af[i], bf[j], acc[i][j], 0, 0, 0);
        }
    }

#pragma unroll
    for (int i = 0; i < 2; i++) {
#pragma unroll
        for (int r = 0; r < 4; r++) {
            int m = m0 + w * 32 + i * 16 + lh * 4 + r;
#pragma unroll
            for (int j = 0; j < 4; j++) {
                int n = n0 + j * 16 + lx;
                float v = acc[i][j][r];
                if (bias) v += bias[n];
                C[(long)m * DM + n] = f2b(v);
            }
        }
    }
}

// ---------------------------------------------------------------------------
// K/V conv-GEMM body (9 x K64 taps; halo via zsrc redirect; bf16 bias).
// ---------------------------------------------------------------------------
__device__ __forceinline__ void conv_body(
    const unsigned short* __restrict__ xvb, const unsigned short* __restrict__ Weff,
    const unsigned short* __restrict__ bias2d, unsigned short* __restrict__ Cout,
    const unsigned short* __restrict__ zsrc, int m0, int n0,
    unsigned short* As, unsigned short* Bs, int t)
{
    int l = t & 63, w = t >> 6;
    int lx = l & 15, lh = l >> 4;
    int wr = w >> 1, wc = w & 1;
    int b = m0 >> 9, s0 = m0 & 511;

    f4v acc[4][4] = {};

    for (int j = 0; j < 9; j++) {
        __syncthreads();
#pragma unroll
        for (int p = 0; p < 4; p++) {
            int flat = p * 256 + t;
            int r = flat >> 3, c = flat & 7;
            int csw = (c ^ (r & 7)) * 8;
            int ss = s0 + r + j - 4;
            const unsigned short* asrc = (ss >= 0 && ss < S)
                ? xvb + ((long)b * S + ss) * VD + csw : zsrc;
            gload16(asrc, As + flat * 8);
            gload16(Weff + (long)(n0 + r) * 640 + j * 64 + csw, Bs + flat * 8);
        }
        __syncthreads();
#pragma unroll
        for (int ks = 0; ks < 2; ks++) {
            s8v af[4], bf[4];
#pragma unroll
            for (int i = 0; i < 4; i++) {
                int ra = wr * 64 + i * 16 + lx;
                af[i] = *(const s8v*)(As + ra * 64 + (((ks * 4 + lh) ^ (ra & 7)) * 8));
                int rb = wc * 64 + i * 16 + lx;
                bf[i] = *(const s8v*)(Bs + rb * 64 + (((ks * 4 + lh) ^ (rb & 7)) * 8));
            }
#pragma unroll
            for (int i = 0; i < 4; i++)
#pragma unroll
                for (int jj = 0; jj < 4; jj++)
                    acc[i][jj] = __builtin_amdgcn_mfma_f32_16x16x32_bf16(
                        af[i], bf[jj], acc[i][jj], 0, 0, 0);
        }
    }

#pragma unroll
    for (int i = 0; i < 4; i++) {
#pragma unroll
        for (int r = 0; r < 4; r++) {
            int m = m0 + wr * 64 + i * 16 + lh * 4 + r;
            int s = m & 511;
#pragma unroll
            for (int jj = 0; jj < 4; jj++) {
                int n = n0 + wc * 64 + jj * 16 + lx;
                Cout[(long)m * DM + n] =
                    f2b(acc[i][jj][r] + b2f(bias2d[(long)s * DM + n]));
            }
        }
    }
}

// ---------------------------------------------------------------------------
// Launch 1: fused cast (7 buffers) + precompute tables (round-9 verbatim).
// ---------------------------------------------------------------------------
__global__ __launch_bounds__(256) void prep_cast_k(
    CastArgs a,
    const float* __restrict__ w3, const float* __restrict__ w5,
    const float* __restrict__ w7, const float* __restrict__ dw_w,
    const float* __restrict__ rel_table, const float* __restrict__ b3,
    const float* __restrict__ b5, const float* __restrict__ b7,
    const float* __restrict__ dw_b,
    unsigned short* __restrict__ WpeT, unsigned short* __restrict__ Cp)
{
    int t = threadIdx.x;
    int y = blockIdx.y;

    if (y < 7) {
        const float* s = a.src[y];
        unsigned short* d = a.dst[y];
        int n = a.n[y];
        float sc = a.scale[y];
        for (long i = (long)(blockIdx.x * 256 + t) * 4; i < n;
             i += (long)gridDim.x * 1024) {
            float4 f = *(const float4*)(s + i);
            ushort4 o;
            o.x = f2b(f.x * sc); o.y = f2b(f.y * sc);
            o.z = f2b(f.z * sc); o.w = f2b(f.w * sc);
            *(ushort4*)(d + i) = o;
        }
        return;
    }

    if (t >= 192) return;
    int o = t;
    float inv = 1.0f / S;

    if (blockIdx.x < 640) {
        int n = blockIdx.x;
        if (n >= 576) { WpeT[n * D3 + o] = 0; return; }
        int j = n >> 6, c = n & 63, delta = j - 4;
        const float* w; int KW, P, oo;
        if (o < 64)       { w = w3; KW = 3; P = 1; oo = o; }
        else if (o < 128) { w = w5; KW = 5; P = 2; oo = o - 64; }
        else              { w = w7; KW = 7; P = 3; oo = o - 128; }
        float mu0 = dw_w[o * 3 + 0] * inv;
        float mu1 = 1.f + (dw_w[o * 3 + 1] - 1.f) * inv;
        float mu2 = dw_w[o * 3 + 2] * inv;
        float acc = 0.f;
        int k;
        k = delta + 1 + P; if (k >= 0 && k < KW) acc += mu0 * w[(oo * 64 + c) * KW + k];
        k = delta + P;     if (k >= 0 && k < KW) acc += mu1 * w[(oo * 64 + c) * KW + k];
        k = delta - 1 + P; if (k >= 0 && k < KW) acc += mu2 * w[(oo * 64 + c) * KW + k];
        WpeT[n * D3 + o] = f2b(acc);
        return;
    }

    int j = blockIdx.x - 640;
    float acc = 0.f;
#pragma unroll
    for (int r = 1; r < 60; r++) {
        int i = j - (r - 30);
        if (i >= 0 && i < S) acc += rel_table[r * D3 + o];
    }
    float c60 = (float)max(0, j - 29);
    float c0  = (float)max(0, (S - 30) - j);
    acc += c60 * rel_table[60 * D3 + o] + c0 * rel_table[0 * D3 + o];
    float mean_rel = acc * inv;

    float bo  = (o < 64) ? b3[o] : (o < 128) ? b5[o - 64] : b7[o - 128];
    float dw0 = dw_w[o * 3], dw1 = dw_w[o * 3 + 1], dw2 = dw_w[o * 3 + 2];
    float r29 = rel_table[29 * D3 + o], r30 = rel_table[30 * D3 + o],
          r31 = rel_table[31 * D3 + o];
    float alpha = 1.f + (dw1 - 1.f) * inv, beta = dw0 * inv, gamma = dw2 * inv;

    float cp = mean_rel + bo * alpha + (dw1 * r30 + dw_b[o] - r30) * inv;
    if (j > 0)     cp += beta * bo + dw0 * r29 * inv;
    if (j < S - 1) cp += gamma * bo + dw2 * r31 * inv;
    Cp[j * D3 + o] = f2b(cp);
}

// ---------------------------------------------------------------------------
// Launch 2: unified small-GEMM dispatch (round-9 verbatim), grid (32,5,5).
// ---------------------------------------------------------------------------
__global__ __launch_bounds__(256) void pre_gemm5_k(
    const unsigned short* __restrict__ wk_bf,
    const unsigned short* __restrict__ wv_bf,
    const unsigned short* __restrict__ WpeT,
    const unsigned short* __restrict__ Cp,
    const unsigned short* __restrict__ xv_bf,
    const unsigned short* __restrict__ wg_bf,
    unsigned short* __restrict__ WEff,
    unsigned short* __restrict__ Cb,
    unsigned short* __restrict__ gamma_bf)
{
    int z = blockIdx.z, mx = blockIdx.x, ny = blockIdx.y;
    const unsigned short *A, *Bm;
    unsigned short* C;
    int K, lda, ldb, ldc;
    if (z < 2) {
        if (mx >= 4) return;
        A = z ? wv_bf : wk_bf; Bm = WpeT; C = WEff + (long)z * DM * 640;
        K = D3; lda = D3; ldb = D3; ldc = 640;
    } else if (z < 4) {
        if (mx >= 4 || ny >= 4) return;
        A = Cp; Bm = (z == 2) ? wk_bf : wv_bf; C = Cb + (long)(z - 2) * S * DM;
        K = D3; lda = D3; ldb = D3; ldc = DM;
    } else {
        if (ny >= 4) return;
        A = xv_bf; Bm = wg_bf; C = gamma_bf;
        K = VD; lda = VD; ldb = VD; ldc = DM;
    }

    __shared__ __align__(16) unsigned short As[128 * 64];
    __shared__ __align__(16) unsigned short Bs[128 * 64];
    gemm128_body(A, Bm, C, nullptr, K, lda, ldb, ldc,
                 mx * 128, ny * 128, As, Bs, threadIdx.x);
}

// ---------------------------------------------------------------------------
// Launch 3: Q projection (128x64 tiles, 512 blocks) + K/V conv (128^2),
// grid (64, 8, 3).
// ---------------------------------------------------------------------------
__global__ __launch_bounds__(256) void qconv_k(
    const unsigned short* __restrict__ xs_bf,
    const unsigned short* __restrict__ wq_bf,
    unsigned short* __restrict__ qbuf,
    const unsigned short* __restrict__ xvb,
    const unsigned short* __restrict__ Weff0,
    const unsigned short* __restrict__ bias0,
    unsigned short* __restrict__ Cout0,
    const unsigned short* __restrict__ zsrc)
{
    __shared__ __align__(16) unsigned short As[128 * 64];
    __shared__ __align__(16) unsigned short Bs[128 * 64];
    int zt = blockIdx.z, t = threadIdx.x;

    if (zt == 0) {                       // Q: 64 x 8 = 512 tiles of 128x64
        gemm_mn64_body(xs_bf, wq_bf, qbuf, nullptr, DM,
                       blockIdx.x * 128, blockIdx.y * 64, As, Bs, t);
        return;
    }
    if (blockIdx.x >= 32 || blockIdx.y >= 4) return;
    int z = zt - 1;
    conv_body(xvb, Weff0 + (long)z * DM * 640, bias0 + (long)z * S * DM,
              Cout0 + (long)z * B * S * DM, zsrc,
              blockIdx.x * 128, blockIdx.y * 128, As, Bs, t);
}

// ---------------------------------------------------------------------------
// Launch 4: MFMA flash attention, QBLK=128 (2 Q-subtiles per wave).
// No-max base-2 softmax; K/V reg prefetch (T14); setprio (T5).
// grid (L/128, H, B) = (8, 8, 8) = 512 blocks; LDS 48 KB.
// ---------------------------------------------------------------------------
__global__ __launch_bounds__(256) void attn_mfma_k(
    const unsigned short* __restrict__ qb, const unsigned short* __restrict__ kb,
    const unsigned short* __restrict__ vb, unsigned short* __restrict__ ob)
{
    __shared__ __align__(16) unsigned short Qs[128 * 64];   // 16 KB
    __shared__ __align__(16) unsigned short Ks[64 * 64];    //  8 KB
    __shared__ __align__(16) unsigned short Vt[64 * 64];    //  8 KB
    __shared__ __align__(16) unsigned short Ps[128 * 64];   // 16 KB

    int lt = blockIdx.x, h = blockIdx.y, b = blockIdx.z;
    int t = threadIdx.x, l = t & 63, w = t >> 6, lx = l & 15, lh = l >> 4;

    const unsigned short* qg = qb + ((long)(b * L + lt * 128)) * DM + h * 64;
    const unsigned short* kg = kb + ((long)b * S) * DM + h * 64;
    const unsigned short* vg = vb + ((long)b * S) * DM + h * 64;

    // stage Q (128 x 64)
#pragma unroll
    for (int pp = 0; pp < 4; pp++) {
        int flat = pp * 256 + t;
        int r = flat >> 3, c = flat & 7;
        s8v v = *(const s8v*)(qg + (long)r * DM + c * 8);
        *(s8v*)(Qs + r * 64 + ((c ^ (r & 7)) * 8)) = v;
    }

    int kr0 = t >> 3, kc = t & 7;          // K staging coords
    int vs = t & 63, vdq = t >> 6;         // V staging coords
    s8v k0, k1, v0, v1;

    auto loadKV = [&](int st) {
        k0 = *(const s8v*)(kg + (long)(st * 64 + kr0) * DM + kc * 8);
        k1 = *(const s8v*)(kg + (long)(st * 64 + 32 + kr0) * DM + kc * 8);
        const unsigned short* vp = vg + (long)(st * 64 + vs) * DM + vdq * 16;
        v0 = *(const s8v*)(vp);
        v1 = *(const s8v*)(vp + 8);
    };
    auto writeKV = [&]() {
        *(s8v*)(Ks + kr0 * 64 + ((kc ^ (kr0 & 7)) * 8)) = k0;
        int r2 = 32 + kr0;
        *(s8v*)(Ks + r2 * 64 + ((kc ^ (r2 & 7)) * 8)) = k1;
#pragma unroll
        for (int e = 0; e < 8; e++) {
            int d1 = vdq * 16 + e;
            Vt[d1 * 64 + (((vs >> 3) ^ (d1 & 7)) * 8) + (vs & 7)] = (unsigned short)v0[e];
            int d2 = vdq * 16 + 8 + e;
            Vt[d2 * 64 + (((vs >> 3) ^ (d2 & 7)) * 8) + (vs & 7)] = (unsigned short)v1[e];
        }
    };

    loadKV(0);
    writeKV();
    __syncthreads();

    float lrow[2][4] = {};
    f4v oacc[2][4] = {};

    for (int st = 0; st < S / 64; st++) {
        if (st < S / 64 - 1) loadKV(st + 1);          // prefetch next tile

        // P = Q K^T over both Q-subtiles (scale*log2e folded into Q)
        f4v pacc[2][4] = {};
        __builtin_amdgcn_s_setprio(1);
#pragma unroll
        for (int sub = 0; sub < 2; sub++)
#pragma unroll
        for (int ks = 0; ks < 2; ks++) {
            int qr = sub * 64 + w * 16 + lx;
            s8v a = *(const s8v*)(Qs + qr * 64 + (((ks * 4 + lh) ^ (qr & 7)) * 8));
#pragma unroll
            for (int jf = 0; jf < 4; jf++) {
                int kr = jf * 16 + lx;
                s8v bf = *(const s8v*)(Ks + kr * 64 + (((ks * 4 + lh) ^ (kr & 7)) * 8));
                pacc[sub][jf] = __builtin_amdgcn_mfma_f32_16x16x32_bf16(
                    a, bf, pacc[sub][jf], 0, 0, 0);
            }
        }
        __builtin_amdgcn_s_setprio(0);

        // softmax-lite: p = 2^x, row sums, store bf16 P (wave-local rows)
#pragma unroll
        for (int sub = 0; sub < 2; sub++)
#pragma unroll
        for (int r = 0; r < 4; r++) {
            int prow = sub * 64 + w * 16 + lh * 4 + r;
#pragma unroll
            for (int jf = 0; jf < 4; jf++) {
                float pe = __builtin_amdgcn_exp2f(pacc[sub][jf][r]);
                lrow[sub][r] += pe;
                int col = jf * 16 + lx;
                Ps[prow * 64 + (((col >> 3) ^ (prow & 7)) * 8) + (col & 7)] = f2b(pe);
            }
        }
        asm volatile("s_waitcnt lgkmcnt(0)" ::: "memory");   // wave-local P vis

        // O += P V for both subtiles
        __builtin_amdgcn_s_setprio(1);
#pragma unroll
        for (int sub = 0; sub < 2; sub++)
#pragma unroll
        for (int ks2 = 0; ks2 < 2; ks2++) {
            int pr = sub * 64 + w * 16 + lx;
            s8v pa = *(const s8v*)(Ps + pr * 64 + (((ks2 * 4 + lh) ^ (pr & 7)) * 8));
#pragma unroll
            for (int df = 0; df < 4; df++) {
                int vr = df * 16 + lx;
                s8v vf = *(const s8v*)(Vt + vr * 64 + (((ks2 * 4 + lh) ^ (vr & 7)) * 8));
                oacc[sub][df] = __builtin_amdgcn_mfma_f32_16x16x32_bf16(
                    pa, vf, oacc[sub][df], 0, 0, 0);
            }
        }
        __builtin_amdgcn_s_setprio(0);
        __syncthreads();                   // all waves done with Ks/Vt
        if (st < S / 64 - 1) {
            writeKV();                     // commit prefetched tile
            __syncthreads();
        }
    }

    // epilogue: lane-reduce l per row, write O/l
#pragma unroll
    for (int sub = 0; sub < 2; sub++) {
        unsigned short* og = ob +
            ((long)(b * L + lt * 128 + sub * 64 + w * 16)) * DM + h * 64;
#pragma unroll
        for (int r = 0; r < 4; r++) {
            float ls = lrow[sub][r];
#pragma unroll
            for (int msk = 1; msk < 16; msk <<= 1) ls += __shfl_xor(ls, msk);
            float invl = 1.f / ls;
#pragma unroll
            for (int df = 0; df < 4; df++)
                og[(long)(lh * 4 + r) * DM + df * 16 + lx] =
                    f2b(oacc[sub][df][r] * invl);
        }
    }
}

// ---------------------------------------------------------------------------
// Launch 5: fc GEMM, 128x64 tiles (512 blocks), bf16 out + f32 bias.
// ---------------------------------------------------------------------------
__global__ __launch_bounds__(256) void gemm_fc_k(
    const unsigned short* __restrict__ A, const unsigned short* __restrict__ Bm,
    unsigned short* __restrict__ Cout, const float* __restrict__ bias)
{
    __shared__ __align__(16) unsigned short As[128 * 64];
    __shared__ __align__(16) unsigned short Bs[128 * 64];
    gemm_mn64_body(A, Bm, Cout, bias, DM,
                   blockIdx.x * 128, blockIdx.y * 64, As, Bs, threadIdx.x);
}

// ---------------------------------------------------------------------------
// Launch 6: out = LN( x_spatial + sigmoid(gamma) * fc_out ) (round-9 verbatim)
// ---------------------------------------------------------------------------
__global__ __launch_bounds__(256) void final_k(
    const float* __restrict__ xs, const unsigned short* __restrict__ fcb,
    const unsigned short* __restrict__ gb,
    const float* __restrict__ ln_g, const float* __restrict__ ln_b,
    float* __restrict__ out)
{
    int bl = blockIdx.x;
    int b = bl >> 10, lq = bl & 1023;
    int t = threadIdx.x;
    int d0 = t * 2;
    const unsigned short* g = gb + ((long)b * S + (lq & 511)) * DM;

    __shared__ float red[2][4];

    float2 xv2 = *(const float2*)(xs + (long)bl * DM + d0);
    unsigned int fp = *(const unsigned int*)(fcb + (long)bl * DM + d0);
    unsigned int gp = *(const unsigned int*)(g + d0);

    float fo0 = b2f(fp & 0xffffu), fo1 = b2f(fp >> 16);
    float ga0 = 1.f / (1.f + __expf(-b2f(gp & 0xffffu)));
    float ga1 = 1.f / (1.f + __expf(-b2f(gp >> 16)));
    float r0 = xv2.x + ga0 * fo0;
    float r1 = xv2.y + ga1 * fo1;

    float sum = r0 + r1, sumsq = r0 * r0 + r1 * r1;
#pragma unroll
    for (int msk = 1; msk < 64; msk <<= 1) {
        sum   += __shfl_xor(sum, msk);
        sumsq += __shfl_xor(sumsq, msk);
    }
    int wave = t >> 6;
    if ((t & 63) == 0) { red[0][wave] = sum; red[1][wave] = sumsq; }
    __syncthreads();
    float tot   = red[0][0] + red[0][1] + red[0][2] + red[0][3];
    float totsq = red[1][0] + red[1][1] + red[1][2] + red[1][3];

    float mu  = tot * (1.0f / DM);
    float var = totsq * (1.0f / DM) - mu * mu;
    float inv = rsqrtf(var + 1e-5f);

    float2 lg = *(const float2*)(ln_g + d0);
    float2 lb = *(const float2*)(ln_b + d0);
    float2 o;
    o.x = (r0 - mu) * inv * lg.x + lb.x;
    o.y = (r1 - mu) * inv * lg.y + lb.y;
    *(float2*)(out + (long)bl * DM + d0) = o;
}

// ---------------------------------------------------------------------------
// Launch
// ---------------------------------------------------------------------------
extern "C" void kernel_launch(void* const* d_in, const int* in_sizes, int n_in,
                              void* d_out, int out_size, void* d_ws, size_t ws_size,
                              hipStream_t stream) {
    (void)in_sizes; (void)n_in; (void)out_size; (void)ws_size;

    const float* x_spatial  = (const float*)d_in[0];
    const float* x_velocity = (const float*)d_in[1];
    const float* w_gamma    = (const float*)d_in[2];
    const float* w3 = (const float*)d_in[3];
    const float* b3 = (const float*)d_in[4];
    const float* w5 = (const float*)d_in[5];
    const float* b5 = (const float*)d_in[6];
    const float* w7 = (const float*)d_in[7];
    const float* b7 = (const float*)d_in[8];
    const float* rel_table = (const float*)d_in[9];
    const float* dw_w = (const float*)d_in[10];
    const float* dw_b = (const float*)d_in[11];
    const float* wq   = (const float*)d_in[12];
    const float* wk   = (const float*)d_in[13];
    const float* wv   = (const float*)d_in[14];
    const float* fc_w = (const float*)d_in[15];
    const float* fc_b = (const float*)d_in[16];
    const float* ln_g = (const float*)d_in[17];
    const float* ln_b = (const float*)d_in[18];
    float* out = (float*)d_out;

    char* pw = (char*)d_ws;
    auto alloc = [&](size_t bytes) {
        char* r = pw;
        pw += (bytes + 255) & ~(size_t)255;
        return r;
    };
    unsigned short* gamma_bf = (unsigned short*)alloc((size_t)B * S * DM * 2);
    unsigned short* fcb      = (unsigned short*)alloc((size_t)B * L * DM * 2);
    unsigned short* xs_bf   = (unsigned short*)alloc((size_t)B * L * DM * 2);
    unsigned short* xv_bf   = (unsigned short*)alloc((size_t)B * S * VD * 2);
    unsigned short* qbuf    = (unsigned short*)alloc((size_t)B * L * DM * 2);
    unsigned short* kvbuf   = (unsigned short*)alloc((size_t)2 * B * S * DM * 2);  // K then V
    unsigned short* attn_bf = (unsigned short*)alloc((size_t)B * L * DM * 2);
    unsigned short* wq_bf   = (unsigned short*)alloc((size_t)DM * DM * 2);
    unsigned short* wk_bf   = (unsigned short*)alloc((size_t)DM * D3 * 2);
    unsigned short* wv_bf   = (unsigned short*)alloc((size_t)DM * D3 * 2);
    unsigned short* fcw_bf  = (unsigned short*)alloc((size_t)DM * DM * 2);
    unsigned short* wg_bf   = (unsigned short*)alloc((size_t)DM * VD * 2);
    unsigned short* WpeT    = (unsigned short*)alloc((size_t)640 * D3 * 2);
    unsigned short* Cp      = (unsigned short*)alloc((size_t)S * D3 * 2);
    unsigned short* WkEff   = (unsigned short*)alloc((size_t)2 * DM * 640 * 2);    // K then V
    unsigned short* Ckb     = (unsigned short*)alloc((size_t)2 * S * DM * 2);      // K then V

    // 1) cast to bf16 (wq scaled by 0.125*log2e for base-2 softmax) + tables
    CastArgs ca;
    ca.src[0] = x_spatial;  ca.dst[0] = xs_bf;  ca.n[0] = B * L * DM; ca.scale[0] = 1.f;
    ca.src[1] = x_velocity; ca.dst[1] = xv_bf;  ca.n[1] = B * S * VD; ca.scale[1] = 1.f;
    ca.src[2] = wq;         ca.dst[2] = wq_bf;  ca.n[2] = DM * DM;    ca.scale[2] = 0.125f * 1.44269504089f;
    ca.src[3] = wk;         ca.dst[3] = wk_bf;  ca.n[3] = DM * D3;    ca.scale[3] = 1.f;
    ca.src[4] = wv;         ca.dst[4] = wv_bf;  ca.n[4] = DM * D3;    ca.scale[4] = 1.f;
    ca.src[5] = fc_w;       ca.dst[5] = fcw_bf; ca.n[5] = DM * DM;    ca.scale[5] = 1.f;
    ca.src[6] = w_gamma;    ca.dst[6] = wg_bf;  ca.n[6] = DM * VD;    ca.scale[6] = 1.f;
    prep_cast_k<<<dim3(1152, 8), 256, 0, stream>>>(
        ca, w3, w5, w7, dw_w, rel_table, b3, b5, b7, dw_b, WpeT, Cp);

    // 2) all small GEMMs: WkEff/WvEff + Ckb/Cvb + gamma
    pre_gemm5_k<<<dim3(32, 5, 5), 256, 0, stream>>>(
        wk_bf, wv_bf, WpeT, Cp, xv_bf, wg_bf, WkEff, Ckb, gamma_bf);

    // 3) Q projection (128x64) + K/V conv-GEMM
    qconv_k<<<dim3(64, 8, 3), 256, 0, stream>>>(
        xs_bf, wq_bf, qbuf, xv_bf, WkEff, Ckb, kvbuf, WkEff + 576);

    // 4) attention (QBLK=128)
    attn_mfma_k<<<dim3(L / 128, H, B), 256, 0, stream>>>(
        qbuf, kvbuf, kvbuf + (long)B * S * DM, attn_bf);

    // 5) fc (128x64 tiles)
    gemm_fc_k<<<dim3(64, 8), 256, 0, stream>>>(attn_bf, fcw_bf, fcb, fc_b);

    // 6) gated residual + LayerNorm
    final_k<<<dim3(B * L), 256, 0, stream>>>(
        x_spatial, fcb, gamma_bf, ln_g, ln_b, out);
}